// Round 1
// baseline (2924.808 us; speedup 1.0000x reference)
//
#include <hip/hip_runtime.h>
#include <hip/hip_bf16.h>
#include <math.h>

#define N_NODES 50000
#define DEG 16
#define FIN 256
#define FOUT 128
#define HID 128
#define FG 512            // 4*HID
#define NEDGE (N_NODES*DEG)

// ---------------- helpers ----------------
static __device__ __forceinline__ float u2f(unsigned int u){ union {unsigned int u; float f;} v; v.u=u; return v.f; }
static __device__ __forceinline__ unsigned int f2u(float f){ union {float f; unsigned int u;} v; v.f=f; return v.u; }
static __device__ __forceinline__ float sigm(float x){ return 1.f/(1.f + __expf(-x)); }
// tanh safe at both ends: exp overflow -> 1, underflow -> -1
static __device__ __forceinline__ float tanhx(float x){ return 1.f - 2.f/(__expf(2.f*x) + 1.f); }

// ---------------- K0: init global-max key ----------------
__global__ void k0_init(unsigned int* __restrict__ gmax_key){
  if (threadIdx.x == 0) *gmax_key = 0u;   // 0 < encode(any finite float incl -inf-ish)
}

// ---------------- K1: proj = x@Wp^T (->ws), skip+bias (->d_out) ----------------
// block: 256 threads = {m in 0..1} x {f in 0..127}; tile of 32 nodes.
__global__ __launch_bounds__(256) void k1_proj_skip(
    const float* __restrict__ x, const float* __restrict__ Wp,
    const float* __restrict__ Ws, const float* __restrict__ bias,
    float* __restrict__ proj, float* __restrict__ out)
{
  const int n0 = blockIdx.x * 32;
  const int m  = threadIdx.x >> 7;
  const int f  = threadIdx.x & 127;
  const float* __restrict__ W = m ? Ws : Wp;
  const float bf = bias[f];

  float acc[32];
  #pragma unroll
  for (int n = 0; n < 32; ++n) acc[n] = 0.f;

  for (int k = 0; k < FIN; k += 4) {
    const float4 w4 = *(const float4*)&W[f*FIN + k];
    #pragma unroll
    for (int n = 0; n < 32; ++n) {
      const int node = (n0 + n < N_NODES) ? (n0 + n) : (N_NODES - 1); // clamp tail, uniform addr
      const float4 x4 = *(const float4*)&x[node*FIN + k];
      acc[n] += w4.x*x4.x + w4.y*x4.y + w4.z*x4.z + w4.w*x4.w;
    }
  }
  #pragma unroll
  for (int n = 0; n < 32; ++n) {
    const int node = n0 + n;
    if (node < N_NODES) {
      if (m == 0) proj[node*FOUT + f] = acc[n];
      else        out [node*FOUT + f] = acc[n] + bf;
    }
  }
}

// ---------------- K1b: s_src/s_trg = proj @ a_src / a_trg (double for stable ordering) ----------------
__global__ __launch_bounds__(256) void k1b_sv(
    const float* __restrict__ proj, const float* __restrict__ a_src,
    const float* __restrict__ a_trg, double* __restrict__ ssrc, double* __restrict__ strg)
{
  const int n = blockIdx.x*256 + threadIdx.x;
  if (n >= N_NODES) return;
  double ss = 0.0, st = 0.0;
  for (int k = 0; k < FOUT; k += 4) {
    const float4 p  = *(const float4*)&proj[n*FOUT + k];
    const float4 as = *(const float4*)&a_src[k];
    const float4 at = *(const float4*)&a_trg[k];
    ss += (double)p.x*as.x + (double)p.y*as.y + (double)p.z*as.z + (double)p.w*as.w;
    st += (double)p.x*at.x + (double)p.y*at.y + (double)p.z*at.z + (double)p.w*at.w;
  }
  ssrc[n] = ss; strg[n] = st;
}

// ---------------- K2: G = proj @ w_ih_b^T -> bf16 (the 16x FLOP-reduction trick) ----------------
__global__ __launch_bounds__(256) void k2_G(
    const float* __restrict__ proj, const float* __restrict__ wih,
    __hip_bfloat16* __restrict__ G)
{
  const int n0 = blockIdx.x * 32;
  const int f0 = threadIdx.x;            // covers rows f0 and f0+256 of [512,128]
  float acc0[32], acc1[32];
  #pragma unroll
  for (int n = 0; n < 32; ++n) { acc0[n] = 0.f; acc1[n] = 0.f; }

  for (int k = 0; k < FOUT; k += 4) {
    const float4 wa = *(const float4*)&wih[f0*FOUT + k];
    const float4 wb = *(const float4*)&wih[(f0+256)*FOUT + k];
    #pragma unroll
    for (int n = 0; n < 32; ++n) {
      const int node = (n0 + n < N_NODES) ? (n0 + n) : (N_NODES - 1);
      const float4 p = *(const float4*)&proj[node*FOUT + k];
      acc0[n] += wa.x*p.x + wa.y*p.y + wa.z*p.z + wa.w*p.w;
      acc1[n] += wb.x*p.x + wb.y*p.y + wb.z*p.z + wb.w*p.w;
    }
  }
  #pragma unroll
  for (int n = 0; n < 32; ++n) {
    const int node = n0 + n;
    if (node < N_NODES) {
      G[node*FG + f0      ] = __float2bfloat16(acc0[n]);
      G[node*FG + f0 + 256] = __float2bfloat16(acc1[n]);
    }
  }
}

// ---------------- K3: edge scores (double) + global max (uint-key atomicMax) ----------------
__global__ __launch_bounds__(256) void k3_scores(
    const double* __restrict__ ssrc, const double* __restrict__ strg,
    const int* __restrict__ esrc, const int* __restrict__ etrg,
    double* __restrict__ scod, unsigned int* __restrict__ gmax_key)
{
  const int n = blockIdx.x*256 + threadIdx.x;
  float lmax = -3.0e38f;
  if (n < N_NODES) {
    const double stn = strg[etrg[n*DEG]];   // trg is n for all 16 edges
    #pragma unroll
    for (int j = 0; j < DEG; ++j) {
      const int e = n*DEG + j;
      double sc = ssrc[esrc[e]] + stn;
      sc = (sc > 0.0) ? sc : 0.2*sc;
      scod[e] = sc;
      lmax = fmaxf(lmax, (float)sc);
    }
  }
  #pragma unroll
  for (int off = 32; off > 0; off >>= 1)
    lmax = fmaxf(lmax, __shfl_down(lmax, off, 64));
  __shared__ float wmax[4];
  if ((threadIdx.x & 63) == 0) wmax[threadIdx.x >> 6] = lmax;
  __syncthreads();
  if (threadIdx.x == 0) {
    const float mv = fmaxf(fmaxf(wmax[0], wmax[1]), fmaxf(wmax[2], wmax[3]));
    const unsigned int u = f2u(mv);
    const unsigned int key = (u & 0x80000000u) ? ~u : (u | 0x80000000u);
    atomicMax(gmax_key, key);
  }
}

// ---------------- K4: softmax att + descending rank (stable, matches reversed argsort) ----------------
__global__ __launch_bounds__(256) void k4_att(
    const double* __restrict__ scod, const int* __restrict__ esrc,
    const unsigned int* __restrict__ gmax_key,
    float* __restrict__ atts, int* __restrict__ srcs)
{
  const int n = blockIdx.x*256 + threadIdx.x;
  if (n >= N_NODES) return;
  const unsigned int key = *gmax_key;
  const unsigned int u = (key & 0x80000000u) ? (key ^ 0x80000000u) : ~key;
  const float gmax = u2f(u);

  double sc[DEG]; float av[DEG]; int si[DEG];
  float sum = 0.f;
  #pragma unroll
  for (int j = 0; j < DEG; ++j) {
    sc[j] = scod[n*DEG + j];
    av[j] = __expf((float)sc[j] - gmax);
    sum  += av[j];
    si[j] = esrc[n*DEG + j];
  }
  const float inv = 1.f/(sum + 1e-16f);
  #pragma unroll
  for (int j = 0; j < DEG; ++j) {
    int r = 0;
    #pragma unroll
    for (int k = 0; k < DEG; ++k)
      r += (sc[k] > sc[j]) || (sc[k] == sc[j] && k > j);
    atts[n*DEG + r] = av[j]*inv;
    srcs[n*DEG + r] = si[j];
  }
}

// ---------------- K5: fused 16-step LSTM + skip + leaky_relu ----------------
// block 512 = {f in 0..127} x {ng in 0..3}; each thread: 4 nodes, all 4 gates of hidden f.
// w_hh in LDS as bf16, two u32 planes (g0|g1),(g2|g3): word index k*128+f -> 2-way bank (free).
#define K5_LDS_BYTES (131072 + 8192 + 1024 + 1024)
__global__ __launch_bounds__(512) void k5_lstm(
    const __hip_bfloat16* __restrict__ G, const float* __restrict__ whh,
    const float* __restrict__ bih, const float* __restrict__ bhh,
    const float* __restrict__ atts, const int* __restrict__ srcs,
    float* __restrict__ out)
{
  extern __shared__ unsigned char smem[];
  unsigned int* w01 = (unsigned int*)smem;                 // [128k][128f]
  unsigned int* w23 = (unsigned int*)(smem + 65536);
  float* hbuf = (float*)(smem + 131072);                   // [16 nodes][128]
  float* attb = (float*)(smem + 131072 + 8192);            // [16][16]
  int*   srcb = (int*)  (smem + 131072 + 8192 + 1024);     // [16][16]
  const int tid = threadIdx.x;
  const int f   = tid & 127;
  const int ng  = tid >> 7;

  { // stage w_hh_b [512,128] fp32 -> bf16 planes (once per block)
    __hip_bfloat16* w01h = (__hip_bfloat16*)w01;
    __hip_bfloat16* w23h = (__hip_bfloat16*)w23;
    for (int idx = tid; idx < FG*HID; idx += 512) {
      const int row = idx >> 7, k = idx & 127;
      const int g = row >> 7, fh = row & 127;
      const __hip_bfloat16 b = __float2bfloat16(whh[idx]);
      if (g < 2) w01h[(k*HID + fh)*2 + g]       = b;
      else       w23h[(k*HID + fh)*2 + (g & 1)] = b;
    }
  }
  float bsum[4];
  #pragma unroll
  for (int g = 0; g < 4; ++g) bsum[g] = bih[g*HID + f] + bhh[g*HID + f];
  __syncthreads();

  #pragma unroll 1
  for (int chunk = blockIdx.x; chunk < N_NODES/16; chunk += gridDim.x) {
    const int nb = chunk*16;                 // 50000 = 3125*16 exactly
    if (tid < 256) {
      attb[tid] = atts[nb*DEG + tid];
      srcb[tid] = srcs[nb*DEG + tid];
    }
    for (int i = tid; i < 16*HID; i += 512) hbuf[i] = 0.f;
    float c[4]    = {0.f,0.f,0.f,0.f};
    float hreg[4] = {0.f,0.f,0.f,0.f};
    __syncthreads();

    #pragma unroll 1
    for (int t = 0; t < DEG; ++t) {
      float acc[4][4];
      #pragma unroll
      for (int nd = 0; nd < 4; ++nd) {          // x-gates: att * G[src] + bias
        const int nl = ng*4 + nd;
        const float at = attb[nl*DEG + t];
        const int  s  = srcb[nl*DEG + t];
        const __hip_bfloat16* gr = G + s*FG + f;
        #pragma unroll
        for (int g = 0; g < 4; ++g)
          acc[nd][g] = bsum[g] + at*__bfloat162float(gr[g*HID]);
      }
      #pragma unroll 1
      for (int k = 0; k < HID; k += 4) {        // recurrent h @ w_hh^T
        float hvv[4][4];
        #pragma unroll
        for (int nd = 0; nd < 4; ++nd) {
          const float4 q = *(const float4*)&hbuf[(ng*4 + nd)*HID + k];  // broadcast read
          hvv[nd][0]=q.x; hvv[nd][1]=q.y; hvv[nd][2]=q.z; hvv[nd][3]=q.w;
        }
        #pragma unroll
        for (int kk = 0; kk < 4; ++kk) {
          const unsigned int wa = w01[(k+kk)*HID + f];
          const unsigned int wb = w23[(k+kk)*HID + f];
          const float wg0 = u2f(wa << 16), wg1 = u2f(wa & 0xffff0000u);
          const float wg2 = u2f(wb << 16), wg3 = u2f(wb & 0xffff0000u);
          #pragma unroll
          for (int nd = 0; nd < 4; ++nd) {
            const float hk = hvv[nd][kk];
            acc[nd][0] += wg0*hk; acc[nd][1] += wg1*hk;
            acc[nd][2] += wg2*hk; acc[nd][3] += wg3*hk;
          }
        }
      }
      #pragma unroll
      for (int nd = 0; nd < 4; ++nd) {          // gate nonlinearities
        const float si = sigm (acc[nd][0]);
        const float sf = sigm (acc[nd][1]);
        const float tg = tanhx(acc[nd][2]);
        const float so = sigm (acc[nd][3]);
        c[nd]    = sf*c[nd] + si*tg;
        hreg[nd] = so*tanhx(c[nd]);
      }
      __syncthreads();                          // all reads of old h done
      if (t < DEG-1) {
        #pragma unroll
        for (int nd = 0; nd < 4; ++nd) hbuf[(ng*4+nd)*HID + f] = hreg[nd];
      }
      __syncthreads();                          // new h visible
    }
    #pragma unroll
    for (int nd = 0; nd < 4; ++nd) {            // out = lrelu(h + skip+bias, 0.01)
      const int node = nb + ng*4 + nd;
      const float v = hreg[nd] + out[node*HID + f];
      out[node*HID + f] = (v > 0.f) ? v : 0.01f*v;
    }
  }
}

// ---------------- launch ----------------
extern "C" void kernel_launch(void* const* d_in, const int* in_sizes, int n_in,
                              void* d_out, int out_size, void* d_ws, size_t ws_size,
                              hipStream_t stream)
{
  (void)in_sizes; (void)n_in; (void)out_size; (void)ws_size;
  const float* x     = (const float*)d_in[0];
  const float* Wp    = (const float*)d_in[1];
  const float* a_src = (const float*)d_in[2];
  const float* a_trg = (const float*)d_in[3];
  const float* Ws    = (const float*)d_in[4];
  const float* bias  = (const float*)d_in[5];
  const float* wih_b = (const float*)d_in[10];
  const float* whh_b = (const float*)d_in[11];
  const float* bih_b = (const float*)d_in[12];
  const float* bhh_b = (const float*)d_in[13];
  const int*   eidx  = (const int*)d_in[14];
  const int* esrc = eidx;
  const int* etrg = eidx + NEDGE;
  float* out = (float*)d_out;

  unsigned char* ws = (unsigned char*)d_ws;
  unsigned int*  gmax = (unsigned int*)(ws + 0);
  float*  proj = (float*) (ws + 256);         // 25,600,000 B
  double* ssrc = (double*)(ws + 25600256);    //    400,000 B
  double* strg = (double*)(ws + 26000256);    //    400,000 B
  double* scod = (double*)(ws + 26400256);    //  6,400,000 B
  float*  atts = (float*) (ws + 32800256);    //  3,200,000 B
  int*    srcs = (int*)   (ws + 36000256);    //  3,200,000 B
  __hip_bfloat16* G = (__hip_bfloat16*)(ws + 39200256); // 51,200,000 B -> total ~90.4 MB

  k0_init<<<dim3(1), dim3(64), 0, stream>>>(gmax);
  k1_proj_skip<<<dim3((N_NODES+31)/32), dim3(256), 0, stream>>>(x, Wp, Ws, bias, proj, out);
  k1b_sv<<<dim3((N_NODES+255)/256), dim3(256), 0, stream>>>(proj, a_src, a_trg, ssrc, strg);
  k2_G<<<dim3((N_NODES+31)/32), dim3(256), 0, stream>>>(proj, wih_b, G);
  k3_scores<<<dim3((N_NODES+255)/256), dim3(256), 0, stream>>>(ssrc, strg, esrc, etrg, scod, gmax);
  k4_att<<<dim3((N_NODES+255)/256), dim3(256), 0, stream>>>(scod, esrc, gmax, atts, srcs);
  hipFuncSetAttribute(reinterpret_cast<const void*>(k5_lstm),
                      hipFuncAttributeMaxDynamicSharedMemorySize, K5_LDS_BYTES);
  k5_lstm<<<dim3(256), dim3(512), K5_LDS_BYTES, stream>>>(G, whh_b, bih_b, bhh_b, atts, srcs, out);
}

// Round 2
// 1160.056 us; speedup vs baseline: 2.5213x; 2.5213x over previous
//
#include <hip/hip_runtime.h>
#include <hip/hip_bf16.h>
#include <math.h>

#define N_NODES 50000
#define DEG 16
#define FIN 256
#define FOUT 128
#define HID 128
#define FG 512            // 4*HID
#define NEDGE (N_NODES*DEG)
#define NCHUNK (N_NODES/16)   // 3125 exactly

typedef __bf16 bf16x8 __attribute__((ext_vector_type(8)));
typedef float  f32x4  __attribute__((ext_vector_type(4)));

// ---------------- helpers ----------------
static __device__ __forceinline__ float u2f(unsigned int u){ union {unsigned int u; float f;} v; v.u=u; return v.f; }
static __device__ __forceinline__ unsigned int f2u(float f){ union {float f; unsigned int u;} v; v.f=f; return v.u; }
static __device__ __forceinline__ unsigned short f2bfu(float f){  // RNE float->bf16 bits
  unsigned int u = f2u(f);
  unsigned int r = u + 0x7fffu + ((u >> 16) & 1u);
  return (unsigned short)(r >> 16);
}
static __device__ __forceinline__ float bflo(unsigned int u){ return u2f(u << 16); }
static __device__ __forceinline__ float bfhi(unsigned int u){ return u2f(u & 0xffff0000u); }
static __device__ __forceinline__ float sigm(float x){ return 1.f/(1.f + __expf(-x)); }
static __device__ __forceinline__ float tanhx(float x){ return 1.f - 2.f/(__expf(2.f*x) + 1.f); }

// ---------------- K0: init global-max key ----------------
__global__ void k0_init(unsigned int* __restrict__ gmax_key){
  if (threadIdx.x == 0) *gmax_key = 0u;
}

// ---------------- K1: proj = x@Wp^T (->ws), skip+bias (->d_out) ----------------
__global__ __launch_bounds__(256) void k1_proj_skip(
    const float* __restrict__ x, const float* __restrict__ Wp,
    const float* __restrict__ Ws, const float* __restrict__ bias,
    float* __restrict__ proj, float* __restrict__ out)
{
  const int n0 = blockIdx.x * 32;
  const int m  = threadIdx.x >> 7;
  const int f  = threadIdx.x & 127;
  const float* __restrict__ W = m ? Ws : Wp;
  const float bf = bias[f];

  float acc[32];
  #pragma unroll
  for (int n = 0; n < 32; ++n) acc[n] = 0.f;

  for (int k = 0; k < FIN; k += 4) {
    const float4 w4 = *(const float4*)&W[f*FIN + k];
    #pragma unroll
    for (int n = 0; n < 32; ++n) {
      const int node = (n0 + n < N_NODES) ? (n0 + n) : (N_NODES - 1);
      const float4 x4 = *(const float4*)&x[node*FIN + k];
      acc[n] += w4.x*x4.x + w4.y*x4.y + w4.z*x4.z + w4.w*x4.w;
    }
  }
  #pragma unroll
  for (int n = 0; n < 32; ++n) {
    const int node = n0 + n;
    if (node < N_NODES) {
      if (m == 0) proj[node*FOUT + f] = acc[n];
      else        out [node*FOUT + f] = acc[n] + bf;
    }
  }
}

// ---------------- K1b: s_src/s_trg (double for stable ordering) ----------------
__global__ __launch_bounds__(256) void k1b_sv(
    const float* __restrict__ proj, const float* __restrict__ a_src,
    const float* __restrict__ a_trg, double* __restrict__ ssrc, double* __restrict__ strg)
{
  const int n = blockIdx.x*256 + threadIdx.x;
  if (n >= N_NODES) return;
  double ss = 0.0, st = 0.0;
  for (int k = 0; k < FOUT; k += 4) {
    const float4 p  = *(const float4*)&proj[n*FOUT + k];
    const float4 as = *(const float4*)&a_src[k];
    const float4 at = *(const float4*)&a_trg[k];
    ss += (double)p.x*as.x + (double)p.y*as.y + (double)p.z*as.z + (double)p.w*as.w;
    st += (double)p.x*at.x + (double)p.y*at.y + (double)p.z*at.z + (double)p.w*at.w;
  }
  ssrc[n] = ss; strg[n] = st;
}

// ---------------- K2: G = proj @ w_ih_b^T -> bf16, GATE-INTERLEAVED [node][f*4+g] ----------------
__global__ __launch_bounds__(256) void k2_G(
    const float* __restrict__ proj, const float* __restrict__ wih,
    __hip_bfloat16* __restrict__ G)
{
  const int n0 = blockIdx.x * 32;
  const int f0 = threadIdx.x;            // rows f0 and f0+256 of [512,128]
  float acc0[32], acc1[32];
  #pragma unroll
  for (int n = 0; n < 32; ++n) { acc0[n] = 0.f; acc1[n] = 0.f; }

  for (int k = 0; k < FOUT; k += 4) {
    const float4 wa = *(const float4*)&wih[f0*FOUT + k];
    const float4 wb = *(const float4*)&wih[(f0+256)*FOUT + k];
    #pragma unroll
    for (int n = 0; n < 32; ++n) {
      const int node = (n0 + n < N_NODES) ? (n0 + n) : (N_NODES - 1);
      const float4 p = *(const float4*)&proj[node*FOUT + k];
      acc0[n] += wa.x*p.x + wa.y*p.y + wa.z*p.z + wa.w*p.w;
      acc1[n] += wb.x*p.x + wb.y*p.y + wb.z*p.z + wb.w*p.w;
    }
  }
  const int g0 = f0 >> 7;        // gate of row f0 (0 or 1)
  const int fh = f0 & 127;       // hidden index
  #pragma unroll
  for (int n = 0; n < 32; ++n) {
    const int node = n0 + n;
    if (node < N_NODES) {
      G[node*FG + fh*4 + g0    ] = __float2bfloat16(acc0[n]);  // gates 0/1
      G[node*FG + fh*4 + g0 + 2] = __float2bfloat16(acc1[n]);  // gates 2/3
    }
  }
}

// ---------------- K3: edge scores (double) + global max ----------------
__global__ __launch_bounds__(256) void k3_scores(
    const double* __restrict__ ssrc, const double* __restrict__ strg,
    const int* __restrict__ esrc, const int* __restrict__ etrg,
    double* __restrict__ scod, unsigned int* __restrict__ gmax_key)
{
  const int n = blockIdx.x*256 + threadIdx.x;
  float lmax = -3.0e38f;
  if (n < N_NODES) {
    const double stn = strg[etrg[n*DEG]];
    #pragma unroll
    for (int j = 0; j < DEG; ++j) {
      const int e = n*DEG + j;
      double sc = ssrc[esrc[e]] + stn;
      sc = (sc > 0.0) ? sc : 0.2*sc;
      scod[e] = sc;
      lmax = fmaxf(lmax, (float)sc);
    }
  }
  #pragma unroll
  for (int off = 32; off > 0; off >>= 1)
    lmax = fmaxf(lmax, __shfl_down(lmax, off, 64));
  __shared__ float wmax[4];
  if ((threadIdx.x & 63) == 0) wmax[threadIdx.x >> 6] = lmax;
  __syncthreads();
  if (threadIdx.x == 0) {
    const float mv = fmaxf(fmaxf(wmax[0], wmax[1]), fmaxf(wmax[2], wmax[3]));
    const unsigned int u = f2u(mv);
    const unsigned int key = (u & 0x80000000u) ? ~u : (u | 0x80000000u);
    atomicMax(gmax_key, key);
  }
}

// ---------------- K4: softmax att + descending rank ----------------
__global__ __launch_bounds__(256) void k4_att(
    const double* __restrict__ scod, const int* __restrict__ esrc,
    const unsigned int* __restrict__ gmax_key,
    float* __restrict__ atts, int* __restrict__ srcs)
{
  const int n = blockIdx.x*256 + threadIdx.x;
  if (n >= N_NODES) return;
  const unsigned int key = *gmax_key;
  const unsigned int u = (key & 0x80000000u) ? (key ^ 0x80000000u) : ~key;
  const float gmax = u2f(u);

  double sc[DEG]; float av[DEG]; int si[DEG];
  float sum = 0.f;
  #pragma unroll
  for (int j = 0; j < DEG; ++j) {
    sc[j] = scod[n*DEG + j];
    av[j] = __expf((float)sc[j] - gmax);
    sum  += av[j];
    si[j] = esrc[n*DEG + j];
  }
  const float inv = 1.f/(sum + 1e-16f);
  #pragma unroll
  for (int j = 0; j < DEG; ++j) {
    int r = 0;
    #pragma unroll
    for (int k = 0; k < DEG; ++k)
      r += (sc[k] > sc[j]) || (sc[k] == sc[j] && k > j);
    atts[n*DEG + r] = av[j]*inv;
    srcs[n*DEG + r] = si[j];
  }
}

// ---------------- K5: MFMA 16-step LSTM + skip + leaky_relu ----------------
// Block 512 = 8 waves; per chunk of 16 nodes:
//   gates[16 nodes x 512] = h[16x128] @ w_hh^T  via mfma_f32_16x16x32_bf16
//   wave w owns hidden f in [w*16, w*16+16), all 4 gates (gate = accumulator idx)
//   -> all 4 gates of one (node,f) land in ONE lane; no cross-lane before nonlin.
// w_hh held in 16 B-fragments in VGPRs (64 regs); h double-buffered bf16 in LDS
// with XOR swizzle (bank-uniform ds_read_b128); x-gates = att*G[src] prefetched
// one step ahead (G is gate-interleaved, 8B/lane/node, coalesced per quad).
__global__ __launch_bounds__(512) void k5_lstm(
    const __hip_bfloat16* __restrict__ G, const float* __restrict__ whh,
    const float* __restrict__ bih, const float* __restrict__ bhh,
    const float* __restrict__ atts, const int* __restrict__ srcs,
    float* __restrict__ out)
{
  __shared__ unsigned short hbuf[2][16*128];   // bf16, XOR-swizzled: [buf][node*128 + ((k>>3)^node)*8 + (k&7)]
  __shared__ float attb[16][16];
  __shared__ int   srcb[16][16];

  const int tid   = threadIdx.x;
  const int wave  = tid >> 6;
  const int lane  = tid & 63;
  const int c     = lane & 15;       // tile column / A-row (node for A-frags)
  const int q     = lane >> 4;       // quad
  const int fbase = wave * 16;
  const int fcol  = fbase + c;       // this lane's hidden index (C columns)
  const int nb0   = q * 4;           // C rows: nodes nb0..nb0+3

  union FU { bf16x8 bf; unsigned short us[8]; uint4 u4; };

  // --- B fragments: B[k][n] = whh[n*128+k], n = g*128+fcol, k = kt*32 + q*8 + j ---
  FU B[4][4];
  #pragma unroll
  for (int g = 0; g < 4; ++g) {
    const float* wr = whh + (g*HID + fcol)*HID + q*8;
    #pragma unroll
    for (int kt = 0; kt < 4; ++kt) {
      const float4 w0 = *(const float4*)(wr + kt*32);
      const float4 w1 = *(const float4*)(wr + kt*32 + 4);
      B[g][kt].us[0]=f2bfu(w0.x); B[g][kt].us[1]=f2bfu(w0.y);
      B[g][kt].us[2]=f2bfu(w0.z); B[g][kt].us[3]=f2bfu(w0.w);
      B[g][kt].us[4]=f2bfu(w1.x); B[g][kt].us[5]=f2bfu(w1.y);
      B[g][kt].us[6]=f2bfu(w1.z); B[g][kt].us[7]=f2bfu(w1.w);
    }
  }
  float bsum[4];
  #pragma unroll
  for (int g = 0; g < 4; ++g) bsum[g] = bih[g*HID + fcol] + bhh[g*HID + fcol];

  // A-frag LDS half-word offsets (node = c, k0 = kt*32+q*8 -> group kt*4+q, XOR-swizzled)
  int aoff[4];
  #pragma unroll
  for (int kt = 0; kt < 4; ++kt)
    aoff[kt] = c*128 + (((kt*4 + q) ^ c) & 15)*8;

  const unsigned short* Gu = (const unsigned short*)G;

  for (int chunk = blockIdx.x; chunk < NCHUNK; chunk += gridDim.x) {
    const int nb = chunk * 16;
    if (tid < 256) {
      ((float*)attb)[tid] = atts[nb*DEG + tid];
      ((int*)srcb)[tid]   = srcs[nb*DEG + tid];
    }
    __syncthreads();

    float cst[4] = {0.f,0.f,0.f,0.f};
    float hv[4]  = {0.f,0.f,0.f,0.f};
    uint2 pf[4];
    #pragma unroll
    for (int r = 0; r < 4; ++r) {
      const int s = srcb[nb0 + r][0];
      pf[r] = *(const uint2*)(Gu + (size_t)s*FG + fcol*4);
    }

    #pragma unroll 4
    for (int t = 0; t < DEG; ++t) {
      uint2 cur[4]; float at[4];
      #pragma unroll
      for (int r = 0; r < 4; ++r) { cur[r] = pf[r]; at[r] = attb[nb0 + r][t]; }
      if (t < DEG-1) {
        #pragma unroll
        for (int r = 0; r < 4; ++r) {
          const int s = srcb[nb0 + r][t+1];
          pf[r] = *(const uint2*)(Gu + (size_t)s*FG + fcol*4);
        }
      }
      // C init: bias + att * x-gate  (gates 0..3 = i,f,g,o packed in cur)
      f32x4 acc[4];
      #pragma unroll
      for (int r = 0; r < 4; ++r) {
        acc[0][r] = bsum[0] + at[r]*bflo(cur[r].x);
        acc[1][r] = bsum[1] + at[r]*bfhi(cur[r].x);
        acc[2][r] = bsum[2] + at[r]*bflo(cur[r].y);
        acc[3][r] = bsum[3] + at[r]*bfhi(cur[r].y);
      }
      if (t > 0) {
        const unsigned short* hb = hbuf[(t-1) & 1];
        FU A[4];
        #pragma unroll
        for (int kt = 0; kt < 4; ++kt) A[kt].u4 = *(const uint4*)(hb + aoff[kt]);
        #pragma unroll
        for (int g = 0; g < 4; ++g) {
          #pragma unroll
          for (int kt = 0; kt < 4; ++kt)
            acc[g] = __builtin_amdgcn_mfma_f32_16x16x32_bf16(A[kt].bf, B[g][kt].bf, acc[g], 0, 0, 0);
        }
      }
      // gate nonlinearities (all 4 gates in-lane)
      #pragma unroll
      for (int r = 0; r < 4; ++r) {
        const float ig = sigm (acc[0][r]);
        const float fg = sigm (acc[1][r]);
        const float gg = tanhx(acc[2][r]);
        const float og = sigm (acc[3][r]);
        cst[r] = fg*cst[r] + ig*gg;
        hv[r]  = og*tanhx(cst[r]);
      }
      if (t < DEG-1) {
        unsigned short* hw = hbuf[t & 1];
        #pragma unroll
        for (int r = 0; r < 4; ++r) {
          const float other = __shfl_xor(hv[r], 1, 64);   // partner lane's value (k^1)
          if ((c & 1) == 0) {
            const unsigned pack = (unsigned)f2bfu(hv[r]) | ((unsigned)f2bfu(other) << 16);
            const int node = nb0 + r;
            const int k = fcol;                            // even
            const int half = node*128 + (((k >> 3) ^ node) & 15)*8 + (k & 7);
            *(unsigned*)(hw + half) = pack;
          }
        }
      }
      __syncthreads();
    }
    // epilogue: out = lrelu(h_final + skip + bias, 0.01)
    #pragma unroll
    for (int r = 0; r < 4; ++r) {
      const int node = nb + nb0 + r;
      const float v = hv[r] + out[node*HID + fcol];
      out[node*HID + fcol] = (v > 0.f) ? v : 0.01f*v;
    }
  }
}

// ---------------- launch ----------------
extern "C" void kernel_launch(void* const* d_in, const int* in_sizes, int n_in,
                              void* d_out, int out_size, void* d_ws, size_t ws_size,
                              hipStream_t stream)
{
  (void)in_sizes; (void)n_in; (void)out_size; (void)ws_size;
  const float* x     = (const float*)d_in[0];
  const float* Wp    = (const float*)d_in[1];
  const float* a_src = (const float*)d_in[2];
  const float* a_trg = (const float*)d_in[3];
  const float* Ws    = (const float*)d_in[4];
  const float* bias  = (const float*)d_in[5];
  const float* wih_b = (const float*)d_in[10];
  const float* whh_b = (const float*)d_in[11];
  const float* bih_b = (const float*)d_in[12];
  const float* bhh_b = (const float*)d_in[13];
  const int*   eidx  = (const int*)d_in[14];
  const int* esrc = eidx;
  const int* etrg = eidx + NEDGE;
  float* out = (float*)d_out;

  unsigned char* ws = (unsigned char*)d_ws;
  unsigned int*  gmax = (unsigned int*)(ws + 0);
  float*  proj = (float*) (ws + 256);
  double* ssrc = (double*)(ws + 25600256);
  double* strg = (double*)(ws + 26000256);
  double* scod = (double*)(ws + 26400256);
  float*  atts = (float*) (ws + 32800256);
  int*    srcs = (int*)   (ws + 36000256);
  __hip_bfloat16* G = (__hip_bfloat16*)(ws + 39200256);

  k0_init<<<dim3(1), dim3(64), 0, stream>>>(gmax);
  k1_proj_skip<<<dim3((N_NODES+31)/32), dim3(256), 0, stream>>>(x, Wp, Ws, bias, proj, out);
  k1b_sv<<<dim3((N_NODES+255)/256), dim3(256), 0, stream>>>(proj, a_src, a_trg, ssrc, strg);
  k2_G<<<dim3((N_NODES+31)/32), dim3(256), 0, stream>>>(proj, wih_b, G);
  k3_scores<<<dim3((N_NODES+255)/256), dim3(256), 0, stream>>>(ssrc, strg, esrc, etrg, scod, gmax);
  k4_att<<<dim3((N_NODES+255)/256), dim3(256), 0, stream>>>(scod, esrc, gmax, atts, srcs);
  k5_lstm<<<dim3(512), dim3(512), 0, stream>>>(G, whh_b, bih_b, bhh_b, atts, srcs, out);
}

// Round 3
// 674.830 us; speedup vs baseline: 4.3341x; 1.7190x over previous
//
#include <hip/hip_runtime.h>
#include <hip/hip_bf16.h>
#include <math.h>

#define N_NODES 50000
#define DEG 16
#define FIN 256
#define FOUT 128
#define HID 128
#define FG 512            // 4*HID
#define NEDGE (N_NODES*DEG)
#define NCHUNK (N_NODES/16)   // 3125 exactly

typedef __bf16 bf16x8 __attribute__((ext_vector_type(8)));
typedef float  f32x4  __attribute__((ext_vector_type(4)));

// ---------------- helpers ----------------
static __device__ __forceinline__ float u2f(unsigned int u){ union {unsigned int u; float f;} v; v.u=u; return v.f; }
static __device__ __forceinline__ unsigned int f2u(float f){ union {float f; unsigned int u;} v; v.f=f; return v.u; }
static __device__ __forceinline__ unsigned short f2bfu(float f){  // RNE float->bf16 bits
  unsigned int u = f2u(f);
  unsigned int r = u + 0x7fffu + ((u >> 16) & 1u);
  return (unsigned short)(r >> 16);
}
static __device__ __forceinline__ float bflo(unsigned int u){ return u2f(u << 16); }
static __device__ __forceinline__ float bfhi(unsigned int u){ return u2f(u & 0xffff0000u); }
static __device__ __forceinline__ float sigm(float x){ return 1.f/(1.f + __expf(-x)); }
static __device__ __forceinline__ float tanhx(float x){ return 1.f - 2.f/(__expf(2.f*x) + 1.f); }

union FU { bf16x8 bf; unsigned short us[8]; uint4 u4; };

// ---------------- K0: init global-max key ----------------
__global__ void k0_init(unsigned int* __restrict__ gmax_key){
  if (threadIdx.x == 0) *gmax_key = 0u;
}

// ---------------- KA: x -> bf16 hi/lo planes ----------------
__global__ __launch_bounds__(256) void k_cvt(
    const float* __restrict__ x, unsigned short* __restrict__ xh, unsigned short* __restrict__ xl)
{
  const int idx = blockIdx.x*256 + threadIdx.x;     // float4 granules
  if (idx >= (N_NODES*FIN)/4) return;
  const float4 v = ((const float4*)x)[idx];
  ushort4 h, l;
  h.x = f2bfu(v.x); l.x = f2bfu(v.x - u2f((unsigned)h.x << 16));
  h.y = f2bfu(v.y); l.y = f2bfu(v.y - u2f((unsigned)h.y << 16));
  h.z = f2bfu(v.z); l.z = f2bfu(v.z - u2f((unsigned)h.z << 16));
  h.w = f2bfu(v.w); l.w = f2bfu(v.w - u2f((unsigned)h.w << 16));
  ((ushort4*)xh)[idx] = h;
  ((ushort4*)xl)[idx] = l;
}

// ---------------- KW: weight converts + v = W^T a (double) ----------------
// blocks 0..255: Wcomb row n ([Wp;Ws], 256 cols) -> Wch/Wcl
// blocks 256..511: wih rows (b-256)*2, +1 -> wihh/wihl
// block 512: vsrc/vtrg[k] = sum_i a[i]*Wp[i,k] in double
__global__ __launch_bounds__(256) void k_w(
    const float* __restrict__ Wp, const float* __restrict__ Ws,
    const float* __restrict__ wih, const float* __restrict__ a_src, const float* __restrict__ a_trg,
    unsigned short* __restrict__ Wch, unsigned short* __restrict__ Wcl,
    unsigned short* __restrict__ wihh, unsigned short* __restrict__ wihl,
    double* __restrict__ vsrc, double* __restrict__ vtrg)
{
  const int b = blockIdx.x, tid = threadIdx.x;
  if (b < 256) {
    const float* src = (b < 128) ? (Wp + b*FIN) : (Ws + (b-128)*FIN);
    const float v = src[tid];
    const unsigned short h = f2bfu(v);
    Wch[b*FIN + tid] = h;
    Wcl[b*FIN + tid] = f2bfu(v - u2f((unsigned)h << 16));
  } else if (b < 512) {
    const int row = (b-256)*2 + (tid >> 7);
    const int k   = tid & 127;
    const float v = wih[row*HID + k];
    const unsigned short h = f2bfu(v);
    wihh[row*HID + k] = h;
    wihl[row*HID + k] = f2bfu(v - u2f((unsigned)h << 16));
  } else {
    const int k = tid;
    double s1 = 0.0, s2 = 0.0;
    for (int i = 0; i < FOUT; ++i) {
      const double w = (double)Wp[i*FIN + k];
      s1 += (double)a_src[i] * w;
      s2 += (double)a_trg[i] * w;
    }
    vsrc[k] = s1; vtrg[k] = s2;
  }
}

// ---------------- KS: s_src/s_trg = x @ v (double) ----------------
__global__ __launch_bounds__(256) void k_s(
    const float* __restrict__ x, const double* __restrict__ vsrc, const double* __restrict__ vtrg,
    double* __restrict__ ssrc, double* __restrict__ strg)
{
  const int n = blockIdx.x*256 + threadIdx.x;
  if (n >= N_NODES) return;
  double ss = 0.0, st = 0.0;
  for (int k = 0; k < FIN; k += 4) {
    const float4 xv = *(const float4*)&x[n*FIN + k];
    ss += xv.x*vsrc[k] + xv.y*vsrc[k+1] + xv.z*vsrc[k+2] + xv.w*vsrc[k+3];
    st += xv.x*vtrg[k] + xv.y*vtrg[k+1] + xv.z*vtrg[k+2] + xv.w*vtrg[k+3];
  }
  ssrc[n] = ss; strg[n] = st;
}

// ---------------- KG: split-bf16 MFMA GEMM, 128x64 tile ----------------
// C[row,col] = sum_k A[row,k]*W[col,k],  A = Ah+Al, W = Wh+Wl (3-pass).
// MODE 0 (KD=256): cols 0..127 -> projh/projl bf16 planes; cols 128..255 -> d_out = C + bias.
// MODE 1 (KD=128): all 512 cols -> G bf16, gate-interleaved (col j <- wih row (j&3)*128+(j>>2)).
template<int KD, int MODE>
__global__ __launch_bounds__(256) void kgemm(
    const unsigned short* __restrict__ Ah_g, const unsigned short* __restrict__ Al_g,
    const unsigned short* __restrict__ Bh_g, const unsigned short* __restrict__ Bl_g,
    const float* __restrict__ bias, float* __restrict__ outf,
    unsigned short* __restrict__ o_h, unsigned short* __restrict__ o_l)
{
  __shared__ unsigned short At[2][128*64];
  __shared__ unsigned short Bt[2][64*64];
  const int tid = threadIdx.x;
  const int bm = blockIdx.x, bn = blockIdx.y;
  const int r0 = bm*128;
  const int wave = tid >> 6, lane = tid & 63, c = lane & 15, q = lane >> 4;
  const int srow = tid >> 3, sg = tid & 7;

  f32x4 acc[2][4];
  #pragma unroll
  for (int rt = 0; rt < 2; ++rt)
    #pragma unroll
    for (int ct = 0; ct < 4; ++ct) acc[rt][ct] = (f32x4){0.f,0.f,0.f,0.f};

  for (int kt = 0; kt < KD/64; ++kt) {
    const int k0 = kt*64;
    __syncthreads();
    // stage A tiles (hi/lo), 4 rounds x 32 rows, XOR-swizzled groups
    #pragma unroll
    for (int rr = 0; rr < 4; ++rr) {
      const int row = rr*32 + srow;
      int grow = r0 + row; if (grow >= N_NODES) grow = N_NODES-1;
      const int ga = grow*KD + k0 + sg*8;
      const int la = row*64 + (((sg ^ (row & 7))) << 3);
      *(uint4*)&At[0][la] = *(const uint4*)&Ah_g[ga];
      *(uint4*)&At[1][la] = *(const uint4*)&Al_g[ga];
    }
    // stage B tiles (hi/lo), 2 rounds x 32 rows
    #pragma unroll
    for (int rr = 0; rr < 2; ++rr) {
      const int row = rr*32 + srow;       // output col within block
      int wr;
      if (MODE == 0) wr = bn*64 + row;
      else { const int j = bn*64 + row; wr = (j & 3)*HID + (j >> 2); }
      const int ga = wr*KD + k0 + sg*8;
      const int la = row*64 + (((sg ^ (row & 7))) << 3);
      *(uint4*)&Bt[0][la] = *(const uint4*)&Bh_g[ga];
      *(uint4*)&Bt[1][la] = *(const uint4*)&Bl_g[ga];
    }
    __syncthreads();

    #pragma unroll
    for (int s = 0; s < 2; ++s) {
      FU Af[2][2], Bf[4][2];
      #pragma unroll
      for (int rt = 0; rt < 2; ++rt) {
        const int row = wave*32 + rt*16 + c;
        const int ad = row*64 + (((((s<<2)+q) ^ (row & 7))) << 3);
        Af[rt][0].u4 = *(const uint4*)&At[0][ad];
        Af[rt][1].u4 = *(const uint4*)&At[1][ad];
      }
      #pragma unroll
      for (int ct = 0; ct < 4; ++ct) {
        const int row = ct*16 + c;
        const int ad = row*64 + (((((s<<2)+q) ^ (row & 7))) << 3);
        Bf[ct][0].u4 = *(const uint4*)&Bt[0][ad];
        Bf[ct][1].u4 = *(const uint4*)&Bt[1][ad];
      }
      #pragma unroll
      for (int rt = 0; rt < 2; ++rt)
        #pragma unroll
        for (int ct = 0; ct < 4; ++ct) {
          acc[rt][ct] = __builtin_amdgcn_mfma_f32_16x16x32_bf16(Af[rt][0].bf, Bf[ct][0].bf, acc[rt][ct], 0,0,0);
          acc[rt][ct] = __builtin_amdgcn_mfma_f32_16x16x32_bf16(Af[rt][1].bf, Bf[ct][0].bf, acc[rt][ct], 0,0,0);
          acc[rt][ct] = __builtin_amdgcn_mfma_f32_16x16x32_bf16(Af[rt][0].bf, Bf[ct][1].bf, acc[rt][ct], 0,0,0);
        }
    }
  }
  __syncthreads();

  if (MODE == 0 && bn >= 2) {
    // skip path: out = C + bias, fp32 direct stores (64B contiguous per quad)
    #pragma unroll
    for (int ct = 0; ct < 4; ++ct) {
      const int col = bn*64 + ct*16 + c - 128;
      const float bv = bias[col];
      #pragma unroll
      for (int rt = 0; rt < 2; ++rt)
        #pragma unroll
        for (int i = 0; i < 4; ++i) {
          const int row = r0 + wave*32 + rt*16 + q*4 + i;
          if (row < N_NODES) outf[row*FOUT + col] = acc[rt][ct][i] + bv;
        }
    }
  } else {
    // bf16 path via LDS roundtrip for contiguous 128B row-chunk stores
    #pragma unroll
    for (int rt = 0; rt < 2; ++rt)
      #pragma unroll
      for (int ct = 0; ct < 4; ++ct)
        #pragma unroll
        for (int i = 0; i < 4; ++i) {
          const int lrow = wave*32 + rt*16 + q*4 + i;
          const int lcol = ct*16 + c;
          const float v = acc[rt][ct][i];
          const unsigned short h = f2bfu(v);
          At[0][lrow*64 + lcol] = h;
          if (MODE == 0) At[1][lrow*64 + lcol] = f2bfu(v - u2f((unsigned)h << 16));
        }
    __syncthreads();
    const int ncols = (MODE == 0) ? FOUT : FG;
    #pragma unroll
    for (int rr = 0; rr < 4; ++rr) {
      const int row = rr*32 + srow;
      const int grow = r0 + row;
      if (grow < N_NODES) {
        const int dst = grow*ncols + bn*64 + sg*8;
        *(uint4*)&o_h[dst] = *(const uint4*)&At[0][row*64 + sg*8];
        if (MODE == 0) *(uint4*)&o_l[dst] = *(const uint4*)&At[1][row*64 + sg*8];
      }
    }
  }
}

// ---------------- K3: edge scores (double) + global max ----------------
__global__ __launch_bounds__(256) void k3_scores(
    const double* __restrict__ ssrc, const double* __restrict__ strg,
    const int* __restrict__ esrc, const int* __restrict__ etrg,
    double* __restrict__ scod, unsigned int* __restrict__ gmax_key)
{
  const int n = blockIdx.x*256 + threadIdx.x;
  float lmax = -3.0e38f;
  if (n < N_NODES) {
    const double stn = strg[etrg[n*DEG]];
    #pragma unroll
    for (int j = 0; j < DEG; ++j) {
      const int e = n*DEG + j;
      double sc = ssrc[esrc[e]] + stn;
      sc = (sc > 0.0) ? sc : 0.2*sc;
      scod[e] = sc;
      lmax = fmaxf(lmax, (float)sc);
    }
  }
  #pragma unroll
  for (int off = 32; off > 0; off >>= 1)
    lmax = fmaxf(lmax, __shfl_down(lmax, off, 64));
  __shared__ float wmax[4];
  if ((threadIdx.x & 63) == 0) wmax[threadIdx.x >> 6] = lmax;
  __syncthreads();
  if (threadIdx.x == 0) {
    const float mv = fmaxf(fmaxf(wmax[0], wmax[1]), fmaxf(wmax[2], wmax[3]));
    const unsigned int u = f2u(mv);
    const unsigned int key = (u & 0x80000000u) ? ~u : (u | 0x80000000u);
    atomicMax(gmax_key, key);
  }
}

// ---------------- K4: softmax att + descending rank ----------------
__global__ __launch_bounds__(256) void k4_att(
    const double* __restrict__ scod, const int* __restrict__ esrc,
    const unsigned int* __restrict__ gmax_key,
    float* __restrict__ atts, int* __restrict__ srcs)
{
  const int n = blockIdx.x*256 + threadIdx.x;
  if (n >= N_NODES) return;
  const unsigned int key = *gmax_key;
  const unsigned int u = (key & 0x80000000u) ? (key ^ 0x80000000u) : ~key;
  const float gmax = u2f(u);

  double sc[DEG]; float av[DEG]; int si[DEG];
  float sum = 0.f;
  #pragma unroll
  for (int j = 0; j < DEG; ++j) {
    sc[j] = scod[n*DEG + j];
    av[j] = __expf((float)sc[j] - gmax);
    sum  += av[j];
    si[j] = esrc[n*DEG + j];
  }
  const float inv = 1.f/(sum + 1e-16f);
  #pragma unroll
  for (int j = 0; j < DEG; ++j) {
    int r = 0;
    #pragma unroll
    for (int k = 0; k < DEG; ++k)
      r += (sc[k] > sc[j]) || (sc[k] == sc[j] && k > j);
    atts[n*DEG + r] = av[j]*inv;
    srcs[n*DEG + r] = si[j];
  }
}

// ---------------- K5: MFMA 16-step LSTM + skip + leaky_relu (unchanged, grid 768) ----------------
__global__ __launch_bounds__(512) void k5_lstm(
    const __hip_bfloat16* __restrict__ G, const float* __restrict__ whh,
    const float* __restrict__ bih, const float* __restrict__ bhh,
    const float* __restrict__ atts, const int* __restrict__ srcs,
    float* __restrict__ out)
{
  __shared__ unsigned short hbuf[2][16*128];
  __shared__ float attb[16][16];
  __shared__ int   srcb[16][16];

  const int tid   = threadIdx.x;
  const int wave  = tid >> 6;
  const int lane  = tid & 63;
  const int c     = lane & 15;
  const int q     = lane >> 4;
  const int fbase = wave * 16;
  const int fcol  = fbase + c;
  const int nb0   = q * 4;

  FU B[4][4];
  #pragma unroll
  for (int g = 0; g < 4; ++g) {
    const float* wr = whh + (g*HID + fcol)*HID + q*8;
    #pragma unroll
    for (int kt = 0; kt < 4; ++kt) {
      const float4 w0 = *(const float4*)(wr + kt*32);
      const float4 w1 = *(const float4*)(wr + kt*32 + 4);
      B[g][kt].us[0]=f2bfu(w0.x); B[g][kt].us[1]=f2bfu(w0.y);
      B[g][kt].us[2]=f2bfu(w0.z); B[g][kt].us[3]=f2bfu(w0.w);
      B[g][kt].us[4]=f2bfu(w1.x); B[g][kt].us[5]=f2bfu(w1.y);
      B[g][kt].us[6]=f2bfu(w1.z); B[g][kt].us[7]=f2bfu(w1.w);
    }
  }
  float bsum[4];
  #pragma unroll
  for (int g = 0; g < 4; ++g) bsum[g] = bih[g*HID + fcol] + bhh[g*HID + fcol];

  int aoff[4];
  #pragma unroll
  for (int kt = 0; kt < 4; ++kt)
    aoff[kt] = c*128 + (((kt*4 + q) ^ c) & 15)*8;

  const unsigned short* Gu = (const unsigned short*)G;

  for (int chunk = blockIdx.x; chunk < NCHUNK; chunk += gridDim.x) {
    const int nb = chunk * 16;
    if (tid < 256) {
      ((float*)attb)[tid] = atts[nb*DEG + tid];
      ((int*)srcb)[tid]   = srcs[nb*DEG + tid];
    }
    __syncthreads();

    float cst[4] = {0.f,0.f,0.f,0.f};
    float hv[4]  = {0.f,0.f,0.f,0.f};
    uint2 pf[4];
    #pragma unroll
    for (int r = 0; r < 4; ++r) {
      const int s = srcb[nb0 + r][0];
      pf[r] = *(const uint2*)(Gu + (size_t)s*FG + fcol*4);
    }

    #pragma unroll 4
    for (int t = 0; t < DEG; ++t) {
      uint2 cur[4]; float at[4];
      #pragma unroll
      for (int r = 0; r < 4; ++r) { cur[r] = pf[r]; at[r] = attb[nb0 + r][t]; }
      if (t < DEG-1) {
        #pragma unroll
        for (int r = 0; r < 4; ++r) {
          const int s = srcb[nb0 + r][t+1];
          pf[r] = *(const uint2*)(Gu + (size_t)s*FG + fcol*4);
        }
      }
      f32x4 acc[4];
      #pragma unroll
      for (int r = 0; r < 4; ++r) {
        acc[0][r] = bsum[0] + at[r]*bflo(cur[r].x);
        acc[1][r] = bsum[1] + at[r]*bfhi(cur[r].x);
        acc[2][r] = bsum[2] + at[r]*bflo(cur[r].y);
        acc[3][r] = bsum[3] + at[r]*bfhi(cur[r].y);
      }
      if (t > 0) {
        const unsigned short* hb = hbuf[(t-1) & 1];
        FU A[4];
        #pragma unroll
        for (int kt = 0; kt < 4; ++kt) A[kt].u4 = *(const uint4*)(hb + aoff[kt]);
        #pragma unroll
        for (int g = 0; g < 4; ++g) {
          #pragma unroll
          for (int kt = 0; kt < 4; ++kt)
            acc[g] = __builtin_amdgcn_mfma_f32_16x16x32_bf16(A[kt].bf, B[g][kt].bf, acc[g], 0, 0, 0);
        }
      }
      #pragma unroll
      for (int r = 0; r < 4; ++r) {
        const float ig = sigm (acc[0][r]);
        const float fg = sigm (acc[1][r]);
        const float gg = tanhx(acc[2][r]);
        const float og = sigm (acc[3][r]);
        cst[r] = fg*cst[r] + ig*gg;
        hv[r]  = og*tanhx(cst[r]);
      }
      if (t < DEG-1) {
        unsigned short* hw = hbuf[t & 1];
        #pragma unroll
        for (int r = 0; r < 4; ++r) {
          const float other = __shfl_xor(hv[r], 1, 64);
          if ((c & 1) == 0) {
            const unsigned pack = (unsigned)f2bfu(hv[r]) | ((unsigned)f2bfu(other) << 16);
            const int node = nb0 + r;
            const int k = fcol;
            const int half = node*128 + (((k >> 3) ^ node) & 15)*8 + (k & 7);
            *(unsigned*)(hw + half) = pack;
          }
        }
      }
      __syncthreads();
    }
    #pragma unroll
    for (int r = 0; r < 4; ++r) {
      const int node = nb + nb0 + r;
      const float v = hv[r] + out[node*HID + fcol];
      out[node*HID + fcol] = (v > 0.f) ? v : 0.01f*v;
    }
  }
}

// ---------------- launch ----------------
// ws layout (bytes):
//  gmax   @ 0          (256)
//  xh     @ 256        (25.6 MB)   \__ G (51.2 MB) aliases xh+xl after kG1 done
//  xl     @ 25600256   (25.6 MB)   /
//  projh  @ 51200256   (12.8 MB)   -> scod (6.4 MB) aliases after kG2 done
//  projl  @ 64000256   (12.8 MB)   -> atts (3.2) + srcs (3.2) alias after kG2 done
//  Wch    @ 76800256  Wcl @ 76931328  wihh @ 77062400  wihl @ 77193472 (128 KB each)
//  vsrc   @ 77324544  vtrg @ 77326592 (2 KB each)
//  ssrc   @ 77328640  strg @ 77728640 (400 KB each)   end ~78.1 MB
extern "C" void kernel_launch(void* const* d_in, const int* in_sizes, int n_in,
                              void* d_out, int out_size, void* d_ws, size_t ws_size,
                              hipStream_t stream)
{
  (void)in_sizes; (void)n_in; (void)out_size; (void)ws_size;
  const float* x     = (const float*)d_in[0];
  const float* Wp    = (const float*)d_in[1];
  const float* a_src = (const float*)d_in[2];
  const float* a_trg = (const float*)d_in[3];
  const float* Ws    = (const float*)d_in[4];
  const float* bias  = (const float*)d_in[5];
  const float* wih_b = (const float*)d_in[10];
  const float* whh_b = (const float*)d_in[11];
  const float* bih_b = (const float*)d_in[12];
  const float* bhh_b = (const float*)d_in[13];
  const int*   eidx  = (const int*)d_in[14];
  const int* esrc = eidx;
  const int* etrg = eidx + NEDGE;
  float* out = (float*)d_out;

  unsigned char* ws = (unsigned char*)d_ws;
  unsigned int*   gmax = (unsigned int*)(ws + 0);
  unsigned short* xh   = (unsigned short*)(ws + 256);
  unsigned short* xl   = (unsigned short*)(ws + 25600256);
  unsigned short* Gh   = (unsigned short*)(ws + 256);          // aliases xh+xl
  unsigned short* projh= (unsigned short*)(ws + 51200256);
  unsigned short* projl= (unsigned short*)(ws + 64000256);
  double*         scod = (double*)(ws + 51200256);             // aliases projh
  float*          atts = (float*) (ws + 64000256);             // aliases projl
  int*            srcs = (int*)   (ws + 67200256);
  unsigned short* Wch  = (unsigned short*)(ws + 76800256);
  unsigned short* Wcl  = (unsigned short*)(ws + 76931328);
  unsigned short* wihh = (unsigned short*)(ws + 77062400);
  unsigned short* wihl = (unsigned short*)(ws + 77193472);
  double*         vsrc = (double*)(ws + 77324544);
  double*         vtrg = (double*)(ws + 77326592);
  double*         ssrc = (double*)(ws + 77328640);
  double*         strg = (double*)(ws + 77728640);

  k0_init<<<dim3(1), dim3(64), 0, stream>>>(gmax);
  k_cvt<<<dim3((N_NODES*FIN/4 + 255)/256), dim3(256), 0, stream>>>(x, xh, xl);
  k_w<<<dim3(513), dim3(256), 0, stream>>>(Wp, Ws, wih_b, a_src, a_trg,
                                           Wch, Wcl, wihh, wihl, vsrc, vtrg);
  k_s<<<dim3((N_NODES+255)/256), dim3(256), 0, stream>>>(x, vsrc, vtrg, ssrc, strg);
  kgemm<FIN,0><<<dim3((N_NODES+127)/128, 4), dim3(256), 0, stream>>>(
      xh, xl, Wch, Wcl, bias, out, projh, projl);
  kgemm<HID,1><<<dim3((N_NODES+127)/128, 8), dim3(256), 0, stream>>>(
      projh, projl, wihh, wihl, bias, out, Gh, (unsigned short*)0);
  k3_scores<<<dim3((N_NODES+255)/256), dim3(256), 0, stream>>>(ssrc, strg, esrc, etrg, scod, gmax);
  k4_att<<<dim3((N_NODES+255)/256), dim3(256), 0, stream>>>(scod, esrc, gmax, atts, srcs);
  k5_lstm<<<dim3(768), dim3(512), 0, stream>>>((const __hip_bfloat16*)Gh, whh_b, bih_b, bhh_b, atts, srcs, out);
}